// Round 1
// baseline (614.142 us; speedup 1.0000x reference)
//
#include <hip/hip_runtime.h>
#include <hip/hip_bf16.h>
#include <math.h>

#define N_V 100000
#define N_E 600000
#define N_F 200000
// CIN = COUT = 128, H = 32

typedef __attribute__((ext_vector_type(8))) short bf16x8;
typedef __attribute__((ext_vector_type(4))) float f32x4;

__device__ __forceinline__ unsigned short f2bf(float f) {
    unsigned int u = __builtin_bit_cast(unsigned int, f);
    u += 0x7fffu + ((u >> 16) & 1u);   // round-to-nearest-even
    return (unsigned short)(u >> 16);
}

// --- K1: face normals, atomic scatter-add to vertex normals ---
__global__ void k_face_normals(const float* __restrict__ vtx,
                               const int* __restrict__ faces,
                               float* __restrict__ nrm) {
    int f = blockIdx.x * blockDim.x + threadIdx.x;
    if (f >= N_F) return;
    int i0 = faces[f], i1 = faces[N_F + f], i2 = faces[2 * N_F + f];
    float ax = vtx[3 * i0], ay = vtx[3 * i0 + 1], az = vtx[3 * i0 + 2];
    float bx = vtx[3 * i1] - ax, by = vtx[3 * i1 + 1] - ay, bz = vtx[3 * i1 + 2] - az;
    float cx = vtx[3 * i2] - ax, cy = vtx[3 * i2 + 1] - ay, cz = vtx[3 * i2 + 2] - az;
    float nx = by * cz - bz * cy;
    float ny = bz * cx - bx * cz;
    float nz = bx * cy - by * cx;
    atomicAdd(&nrm[3 * i0 + 0], nx); atomicAdd(&nrm[3 * i0 + 1], ny); atomicAdd(&nrm[3 * i0 + 2], nz);
    atomicAdd(&nrm[3 * i1 + 0], nx); atomicAdd(&nrm[3 * i1 + 1], ny); atomicAdd(&nrm[3 * i1 + 2], nz);
    atomicAdd(&nrm[3 * i2 + 0], nx); atomicAdd(&nrm[3 * i2 + 1], ny); atomicAdd(&nrm[3 * i2 + 2], nz);
}

// --- K2: normalize vertex normals ---
__global__ void k_norm_normals(float* __restrict__ nrm) {
    int i = blockIdx.x * blockDim.x + threadIdx.x;
    if (i >= N_V) return;
    float x = nrm[3 * i], y = nrm[3 * i + 1], z = nrm[3 * i + 2];
    float inv = 1.f / (sqrtf(x * x + y * y + z * z) + 1e-8f);
    nrm[3 * i] = x * inv; nrm[3 * i + 1] = y * inv; nrm[3 * i + 2] = z * inv;
}

// --- K3: per-edge MLP -> weight w[e]; accumulate den[dst] ---
__global__ void k_edge(const float* __restrict__ vtx, const int* __restrict__ edges,
                       const float* __restrict__ nrm,
                       const float* __restrict__ W1, const float* __restrict__ b1,
                       const float* __restrict__ W2, const float* __restrict__ b2,
                       float* __restrict__ wbuf, float* __restrict__ den) {
    __shared__ float sW1[96], sb1[32], sW2[192], sb2[6];
    int t = threadIdx.x;
    if (t < 96)  sW1[t] = W1[t];
    if (t < 32)  sb1[t] = b1[t];
    if (t < 192) sW2[t] = W2[t];
    if (t < 6)   sb2[t] = b2[t];
    __syncthreads();
    int e = blockIdx.x * blockDim.x + t;
    if (e >= N_E) return;
    int s = edges[e], d = edges[N_E + e];
    float dx = vtx[3 * d] - vtx[3 * s];
    float dy = vtx[3 * d + 1] - vtx[3 * s + 1];
    float dz = vtx[3 * d + 2] - vtx[3 * s + 2];
    float nx = nrm[3 * s], ny = nrm[3 * s + 1], nz = nrm[3 * s + 2];
    float dp = dx * nx + dy * ny + dz * nz;
    float tx = dx - dp * nx, ty = dy - dp * ny, tz = dz - dp * nz;
    float th0 = sb2[0], th1 = sb2[1], th2 = sb2[2], th3 = sb2[3], th4 = sb2[4], th5 = sb2[5];
    #pragma unroll
    for (int j = 0; j < 32; j++) {
        float h = tx * sW1[j] + ty * sW1[32 + j] + tz * sW1[64 + j] + sb1[j];
        h = fmaxf(h, 0.f);
        const float* w2r = &sW2[j * 6];
        th0 += h * w2r[0]; th1 += h * w2r[1]; th2 += h * w2r[2];
        th3 += h * w2r[3]; th4 += h * w2r[4]; th5 += h * w2r[5];
    }
    // S = [[t0,t1,t2],[t1,t3,t4],[t2,t4,t5]]; q = ||S t||^2 (S symmetric)
    float ux = th0 * tx + th1 * ty + th2 * tz;
    float uy = th1 * tx + th3 * ty + th4 * tz;
    float uz = th2 * tx + th4 * ty + th5 * tz;
    float q = ux * ux + uy * uy + uz * uz;
    float w = expf(-q);
    wbuf[e] = w;
    atomicAdd(&den[d], w);
}

// --- K4: aggregate w * features[src] into out[dst] (out pre-zeroed) ---
__global__ void k_aggregate(const float* __restrict__ feat, const int* __restrict__ edges,
                            const float* __restrict__ wbuf, float* __restrict__ out) {
    int t = threadIdx.x;
    int e = blockIdx.x * 2 + (t >> 7);
    int c = t & 127;
    if (e >= N_E) return;
    int s = edges[e], d = edges[N_E + e];
    float w = wbuf[e];
    atomicAdd(&out[d * 128 + c], w * feat[s * 128 + c]);
}

// --- K5: pack Wlin (fp32 [128,128]) into bf16 MFMA B-fragment order ---
// frag flat index = ((kk*8+ct)*64 + lane)*8 + j ; B[k][n], k=kk*32+(lane>>4)*8+j, n=ct*16+(lane&15)
__global__ void k_pack_w(const float* __restrict__ Wlin, unsigned short* __restrict__ Wb) {
    int t = blockIdx.x * blockDim.x + threadIdx.x;
    if (t >= 16384) return;
    int j = t & 7;
    int lane = (t >> 3) & 63;
    int ct = (t >> 9) & 7;
    int kk = t >> 12;
    int k = kk * 32 + (lane >> 4) * 8 + j;
    int n = ct * 16 + (lane & 15);
    Wb[t] = f2bf(Wlin[k * 128 + n]);
}

// --- K6: in-place GEMM: out = (out/den') @ Wlin + blin*(den/den')  [den' = den+eps]
// One wave per 16-row tile, all 128 cols; bf16 MFMA 16x16x32.
__global__ __launch_bounds__(256) void k_gemm(float* __restrict__ out,
                                              const float* __restrict__ den,
                                              const unsigned short* __restrict__ Wb,
                                              const float* __restrict__ blin) {
    int wave = (blockIdx.x * 256 + (int)threadIdx.x) >> 6;
    if (wave >= N_V / 16) return;
    int lane = threadIdx.x & 63;
    int m = lane & 15, quad = lane >> 4;
    int r0 = wave * 16;
    int row_a = r0 + m;
    float dna = den[row_a];
    float sa = 1.f / (dna + 1e-5f);
    const float* arow = out + (size_t)row_a * 128;
    f32x4 acc[8];
    #pragma unroll
    for (int ct = 0; ct < 8; ct++) acc[ct] = (f32x4){0.f, 0.f, 0.f, 0.f};
    #pragma unroll
    for (int kk = 0; kk < 4; kk++) {
        int k0 = kk * 32 + quad * 8;
        float4 a0 = *(const float4*)(arow + k0);
        float4 a1 = *(const float4*)(arow + k0 + 4);
        bf16x8 af;
        af[0] = (short)f2bf(a0.x * sa); af[1] = (short)f2bf(a0.y * sa);
        af[2] = (short)f2bf(a0.z * sa); af[3] = (short)f2bf(a0.w * sa);
        af[4] = (short)f2bf(a1.x * sa); af[5] = (short)f2bf(a1.y * sa);
        af[6] = (short)f2bf(a1.z * sa); af[7] = (short)f2bf(a1.w * sa);
        #pragma unroll
        for (int ct = 0; ct < 8; ct++) {
            bf16x8 bfv = *(const bf16x8*)(Wb + (((kk * 8 + ct) * 64 + lane) << 3));
            acc[ct] = __builtin_amdgcn_mfma_f32_16x16x32_bf16(af, bfv, acc[ct], 0, 0, 0);
        }
    }
    // epilogue: D row = r0 + quad*4 + reg, col = ct*16 + m
    #pragma unroll
    for (int reg = 0; reg < 4; reg++) {
        int r = r0 + quad * 4 + reg;
        float dd = den[r];
        float g = dd / (dd + 1e-5f);
        #pragma unroll
        for (int ct = 0; ct < 8; ct++) {
            int c = ct * 16 + m;
            out[(size_t)r * 128 + c] = acc[ct][reg] + blin[c] * g;
        }
    }
}

// --- K7: column sums / sumsq over rows ---
__global__ void k_stats(const float* __restrict__ out, float* __restrict__ stats) {
    int c = threadIdx.x & 127;
    int half = threadIdx.x >> 7;
    float s = 0.f, s2 = 0.f;
    for (int r = blockIdx.x * 2 + half; r < N_V; r += gridDim.x * 2) {
        float v = out[(size_t)r * 128 + c];
        s += v; s2 += v * v;
    }
    atomicAdd(&stats[c], s);
    atomicAdd(&stats[128 + c], s2);
}

// --- K8: normalize (ddof=1) + ELU, in place ---
__global__ void k_finalize(float* __restrict__ out, const float* __restrict__ stats) {
    int i = blockIdx.x * blockDim.x + threadIdx.x;
    if (i >= N_V * 128) return;
    int c = i & 127;
    float sum = stats[c], sq = stats[128 + c];
    float mu = sum * (1.f / N_V);
    float var = (sq - sum * mu) * (1.f / (N_V - 1));
    float sd = sqrtf(fmaxf(var, 0.f));
    float v = (out[i] - mu) / (sd + 1e-5f);
    out[i] = v > 0.f ? v : expm1f(v);
}

extern "C" void kernel_launch(void* const* d_in, const int* in_sizes, int n_in,
                              void* d_out, int out_size, void* d_ws, size_t ws_size,
                              hipStream_t stream) {
    const float* feat = (const float*)d_in[0];
    const float* vtx  = (const float*)d_in[1];
    const int*   edges = (const int*)d_in[2];
    const int*   faces = (const int*)d_in[3];
    const float* W1   = (const float*)d_in[4];
    const float* b1   = (const float*)d_in[5];
    const float* W2   = (const float*)d_in[6];
    const float* b2   = (const float*)d_in[7];
    const float* Wlin = (const float*)d_in[8];
    const float* blin = (const float*)d_in[9];
    float* out = (float*)d_out;

    float* ws = (float*)d_ws;
    float* nrm   = ws;                 // 300000
    float* den   = ws + 300000;        // 100000
    float* stats = ws + 400000;        // 256
    float* wbuf  = ws + 400256;        // 600000
    unsigned short* Wb = (unsigned short*)(ws + 1000256);  // 16384 shorts

    // zero: normals + den + stats (wbuf/Wb fully overwritten), and d_out (agg target)
    hipMemsetAsync(d_ws, 0, 400256 * sizeof(float), stream);
    hipMemsetAsync(d_out, 0, (size_t)N_V * 128 * sizeof(float), stream);

    k_face_normals<<<(N_F + 255) / 256, 256, 0, stream>>>(vtx, faces, nrm);
    k_norm_normals<<<(N_V + 255) / 256, 256, 0, stream>>>(nrm);
    k_edge<<<(N_E + 255) / 256, 256, 0, stream>>>(vtx, edges, nrm, W1, b1, W2, b2, wbuf, den);
    k_pack_w<<<64, 256, 0, stream>>>(Wlin, Wb);
    k_aggregate<<<N_E / 2, 256, 0, stream>>>(feat, edges, wbuf, out);
    k_gemm<<<(6250 * 64 + 255) / 256, 256, 0, stream>>>(out, den, Wb, blin);
    k_stats<<<256, 256, 0, stream>>>(out, stats);
    k_finalize<<<(N_V * 128 + 255) / 256, 256, 0, stream>>>(out, stats);
}